// Round 8
// baseline (225.163 us; speedup 1.0000x reference)
//
#include <hip/hip_runtime.h>
#include <cmath>

// B=32, N=512, IN=128, HID=32, HEADS=4, OUT=128. fp32 in/out; graph int32.
// 4 dispatches: prep_wt ; gemm_mfma0(x,W0T)->Ht0,e0 ;
//   gat0_gemm(Ht0,e0,graph,W1T)->Ht1,e1 ; gat1_head(Ht1,e1,graph,x,...)->out
// gat m-loops are BARRIER-FREE: P computed per-lane in A-frag layout from
// global graph/e reads; B-frags loaded straight from global Ht (16B/lane).

typedef unsigned short ushort_t;
typedef __attribute__((ext_vector_type(8))) short short8;
typedef __attribute__((ext_vector_type(4))) float f32x4;

__device__ __forceinline__ float gelu_f(float v) {
    return 0.5f * v * (1.0f + erff(v * 0.70710678118654752f));
}
__device__ __forceinline__ ushort_t f2bf(float x) {      // round-to-nearest-even
    union { float f; unsigned u; } v; v.f = x;
    return (ushort_t)((v.u + 0x7FFFu + ((v.u >> 16) & 1u)) >> 16);
}
__device__ __forceinline__ ushort_t f2bf_t(float x) {    // truncate (hot softmax path)
    union { float f; unsigned u; } v; v.f = x;
    return (ushort_t)(v.u >> 16);
}

// ---- prep: bf16-transpose lin_W(256x128) me_W0 me_W1 oh_W W0 W1 (128x128) ---
__global__ __launch_bounds__(256) void prep_wt(const float* __restrict__ lin_W,
        const float* __restrict__ me_W0, const float* __restrict__ me_W1,
        const float* __restrict__ oh_W, const float* __restrict__ W0,
        const float* __restrict__ W1, ushort_t* __restrict__ WT) {
    int i = blockIdx.x * 256 + threadIdx.x;          // 114688 total
    if (i < 32768)       { int c = i >> 8, k = i & 255;                   WT[i] = f2bf(lin_W[k * 128 + c]); }
    else if (i < 49152)  { int j = i - 32768;  int c = j >> 7, k = j & 127; WT[i] = f2bf(me_W0[k * 128 + c]); }
    else if (i < 65536)  { int j = i - 49152;  int c = j >> 7, k = j & 127; WT[i] = f2bf(me_W1[k * 128 + c]); }
    else if (i < 81920)  { int j = i - 65536;  int c = j >> 7, k = j & 127; WT[i] = f2bf(oh_W[k * 128 + c]); }
    else if (i < 98304)  { int j = i - 81920;  int c = j >> 7, k = j & 127; WT[i] = f2bf(W0[k * 128 + c]); }
    else if (i < 114688) { int j = i - 98304;  int c = j >> 7, k = j & 127; WT[i] = f2bf(W1[k * 128 + c]); }
}

// -- 16-row MFMA gemm: Ht[b][c][m] bf16 = (X@W)^T ; fused e_src/e_dst (4 heads)
// Wave w = head w (ct = 2w, 2w+1): e0 reduces wave-internally. A direct from x.
__global__ __launch_bounds__(256) void gemm_mfma0(const float* __restrict__ X,
        const ushort_t* __restrict__ WTr, ushort_t* __restrict__ Ht,
        const float* __restrict__ a_s, const float* __restrict__ a_d,
        float* __restrict__ es, float* __restrict__ ed) {
    __shared__ __align__(16) ushort_t tb[128 * 24];  // 6KB C^T staging
    const int tid = threadIdx.x;
    const int row0 = blockIdx.x * 16;
    const int b = row0 >> 9, m0 = row0 & 511;
    const int wv = tid >> 6, lane = tid & 63;
    const int quad = lane >> 4, lid = lane & 15;
    // A-frags straight from global x
    short8 af[4];
#pragma unroll
    for (int kc = 0; kc < 4; kc++) {
        const float4* xp = (const float4*)(X + (row0 + lid) * 128 + kc * 32 + quad * 8);
        float4 a = xp[0], bb = xp[1];
        short8 p;
        p[0] = (short)f2bf(a.x);  p[1] = (short)f2bf(a.y);
        p[2] = (short)f2bf(a.z);  p[3] = (short)f2bf(a.w);
        p[4] = (short)f2bf(bb.x); p[5] = (short)f2bf(bb.y);
        p[6] = (short)f2bf(bb.z); p[7] = (short)f2bf(bb.w);
        af[kc] = p;
    }
    f32x4 C[2];
    float s0[4] = {0.f, 0.f, 0.f, 0.f}, d0[4] = {0.f, 0.f, 0.f, 0.f};
#pragma unroll
    for (int i = 0; i < 2; i++) {
        int ct = 2 * wv + i;
        const ushort_t* bp = WTr + (ct * 16 + lid) * 128 + quad * 8;
        C[i] = (f32x4){0.f, 0.f, 0.f, 0.f};
#pragma unroll
        for (int kc = 0; kc < 4; kc++) {
            short8 bf = *(const short8*)&bp[kc * 32];
            C[i] = __builtin_amdgcn_mfma_f32_16x16x32_bf16(af[kc], bf, C[i], 0, 0, 0);
        }
        int col = ct * 16 + lid;
        float as_c = a_s[col], ad_c = a_d[col];
#pragma unroll
        for (int r = 0; r < 4; r++) {
            s0[r] = fmaf(C[i][r], as_c, s0[r]);
            d0[r] = fmaf(C[i][r], ad_c, d0[r]);
        }
#pragma unroll
        for (int r = 0; r < 4; r++)
            tb[col * 24 + quad * 4 + r] = f2bf(C[i][r]);
    }
#pragma unroll
    for (int st = 1; st <= 8; st <<= 1)
#pragma unroll
        for (int r = 0; r < 4; r++) {
            s0[r] += __shfl_xor(s0[r], st);
            d0[r] += __shfl_xor(d0[r], st);
        }
    if (lid == 0) {                                  // head wv, rows quad*4+r
#pragma unroll
        for (int r = 0; r < 4; r++) {
            int n = m0 + quad * 4 + r;
            es[(b * 4 + wv) * 512 + n] = s0[r];
            ed[(b * 4 + wv) * 512 + n] = d0[r];
        }
    }
    __syncthreads();
    {   // coalesced Ht store: 128 c x 16 m
        int c = tid >> 1, half = tid & 1;
        *(short8*)&Ht[b * 65536 + c * 512 + m0 + half * 8] = *(const short8*)&tb[c * 24 + half * 8];
    }
}

// ---- K2: gat0 (barrier-free m-loop) -> elu -> gemm vs W1T -> Ht1, e1 --------
__global__ __launch_bounds__(256) void gat0_gemm(const ushort_t* __restrict__ Ht0,
        const float* __restrict__ es0, const float* __restrict__ ed0,
        const int* __restrict__ graph, const ushort_t* __restrict__ W1T,
        const float* __restrict__ a_s, const float* __restrict__ a_d,
        ushort_t* __restrict__ Ht1, float* __restrict__ es1, float* __restrict__ ed1) {
    __shared__ __align__(16) ushort_t abuf[16 * 128];  // 4KB m-tile bf16
    __shared__ __align__(16) ushort_t tb[128 * 24];    // 6KB C^T staging
    __shared__ float2 ered[8 * 16];                    // 1KB e1 partials
    const int tid = threadIdx.x;
    const int b = blockIdx.y, n0 = blockIdx.x * 16;
    const int wv = tid >> 6, lane = tid & 63;          // wv = head (gat) / col pair (gemm)
    const int quad = lane >> 4, lid = lane & 15;
    const int n_mine = n0 + lid;
    const int* gptr = graph + (b * 512 + n_mine) * 512 + quad * 8;
    const float* edp = ed0 + (b * 4 + wv) * 512 + quad * 8;
    const float es_v = es0[(b * 4 + wv) * 512 + n_mine];
    const ushort_t* hb0 = Ht0 + b * 65536 + (wv * 32 + lid) * 512;
    const ushort_t* hb1 = hb0 + 16 * 512;
    const short8 onesf = {0x3F80, 0x3F80, 0x3F80, 0x3F80, 0x3F80, 0x3F80, 0x3F80, 0x3F80};
    f32x4 acc[2], dsf;
    acc[0] = (f32x4){0.f, 0.f, 0.f, 0.f};
    acc[1] = (f32x4){0.f, 0.f, 0.f, 0.f};
    dsf = (f32x4){0.f, 0.f, 0.f, 0.f};
#pragma unroll 4
    for (int mcc = 0; mcc < 16; mcc++) {
        const int mbase = mcc * 32 + quad * 8;
        int4 ga = *(const int4*)(gptr + mcc * 32);
        int4 gb = *(const int4*)(gptr + mcc * 32 + 4);
        float4 e0v = *(const float4*)(edp + mcc * 32);
        float4 e1v = *(const float4*)(edp + mcc * 32 + 4);
        int gv[8] = {ga.x, ga.y, ga.z, ga.w, gb.x, gb.y, gb.z, gb.w};
        float ev[8] = {e0v.x, e0v.y, e0v.z, e0v.w, e1v.x, e1v.y, e1v.z, e1v.w};
        short8 pk;
#pragma unroll
        for (int j = 0; j < 8; j++) {
            float e = es_v + ev[j];
            e = fmaxf(e, 0.2f * e);
            e = ((gv[j] > 0) | ((mbase + j) == n_mine)) ? e : -1e30f;
            pk[j] = (short)f2bf_t(__expf(e));
        }
        short8 b0 = *(const short8*)&hb0[mbase];
        short8 b1 = *(const short8*)&hb1[mbase];
        acc[0] = __builtin_amdgcn_mfma_f32_16x16x32_bf16(pk, b0, acc[0], 0, 0, 0);
        acc[1] = __builtin_amdgcn_mfma_f32_16x16x32_bf16(pk, b1, acc[1], 0, 0, 0);
        dsf = __builtin_amdgcn_mfma_f32_16x16x32_bf16(pk, onesf, dsf, 0, 0, 0);
    }
    // ---- m = elu(softmax-agg) -> bf16 A-tile ----
#pragma unroll
    for (int reg = 0; reg < 4; reg++) {
        float inv = 1.0f / dsf[reg];
        int rw = quad * 4 + reg;
#pragma unroll
        for (int ch = 0; ch < 2; ch++) {
            float v = acc[ch][reg] * inv;
            v = v > 0.f ? v : expm1f(v);            // ELU
            int col = wv * 32 + ch * 16 + lid;
            abuf[rw * 128 + (((col >> 3) ^ (rw & 7)) * 8) + (col & 7)] = f2bf(v);
        }
    }
    __syncthreads();
    // ---- gemm vs W1T + fused e1 (1 head) + Ht1 ----
    short8 af[4];
#pragma unroll
    for (int kc = 0; kc < 4; kc++)
        af[kc] = *(const short8*)&abuf[lid * 128 + (((kc * 4 + quad) ^ (lid & 7)) * 8)];
    f32x4 C[2];
#pragma unroll
    for (int i = 0; i < 2; i++) {
        int ct = wv + 4 * i;
        const ushort_t* bp = W1T + (ct * 16 + lid) * 128 + quad * 8;
        C[i] = (f32x4){0.f, 0.f, 0.f, 0.f};
#pragma unroll
        for (int kc = 0; kc < 4; kc++) {
            short8 bf = *(const short8*)&bp[kc * 32];
            C[i] = __builtin_amdgcn_mfma_f32_16x16x32_bf16(af[kc], bf, C[i], 0, 0, 0);
        }
    }
#pragma unroll
    for (int i = 0; i < 2; i++) {
        int ct = wv + 4 * i, col = ct * 16 + lid;
        float as_c = a_s[col], ad_c = a_d[col];
        float s0[4], d0[4];
#pragma unroll
        for (int r = 0; r < 4; r++) { s0[r] = C[i][r] * as_c; d0[r] = C[i][r] * ad_c; }
#pragma unroll
        for (int st = 1; st <= 8; st <<= 1)
#pragma unroll
            for (int r = 0; r < 4; r++) {
                s0[r] += __shfl_xor(s0[r], st);
                d0[r] += __shfl_xor(d0[r], st);
            }
        if (lid == 0) {
#pragma unroll
            for (int r = 0; r < 4; r++)
                ered[ct * 16 + quad * 4 + r] = make_float2(s0[r], d0[r]);
        }
#pragma unroll
        for (int r = 0; r < 4; r++)
            tb[col * 24 + quad * 4 + r] = f2bf(C[i][r]);
    }
    __syncthreads();
    if (tid < 16) {
        float S = 0.f, D = 0.f;
#pragma unroll
        for (int ct = 0; ct < 8; ct++) { float2 p = ered[ct * 16 + tid]; S += p.x; D += p.y; }
        es1[b * 512 + n0 + tid] = S;
        ed1[b * 512 + n0 + tid] = D;
    }
    {
        int c = tid >> 1, half = tid & 1;
        *(short8*)&Ht1[b * 65536 + c * 512 + n0 + half * 8] = *(const short8*)&tb[c * 24 + half * 8];
    }
}

// ---- K3: gat1 (barrier-free m-loop) -> ln1 -> linear -> MLP -> ln2 -> head --
__global__ __launch_bounds__(256) void gat1_head(const ushort_t* __restrict__ Ht,
        const float* __restrict__ es1, const float* __restrict__ ed1,
        const int* __restrict__ graph, const float* __restrict__ x,
        const float* __restrict__ g1, const float* __restrict__ b1,
        const ushort_t* __restrict__ linT, const float* __restrict__ LB,
        const ushort_t* __restrict__ meT0, const float* __restrict__ B0,
        const ushort_t* __restrict__ meT1, const float* __restrict__ B1,
        const float* __restrict__ g2, const float* __restrict__ b2,
        const ushort_t* __restrict__ ohT, const float* __restrict__ ob,
        const float* __restrict__ g3, const float* __restrict__ b3,
        float* __restrict__ out) {
    __shared__ __align__(16) float    gbuf[16 * 132];  // 8448B G fp32
    __shared__ __align__(16) ushort_t ybuf[16 * 256];  // 8KB ln1 out bf16
    __shared__ __align__(16) ushort_t abuf[16 * 128];  // 4KB m2 bf16
    __shared__ __align__(16) ushort_t tbuf[16 * 128];  // 4KB phase scratch
    __shared__ float2 red[4 * 16];
    __shared__ float2 mvs[16];
    const int tid = threadIdx.x;
    const int b = blockIdx.y, n0 = blockIdx.x * 16;
    const int wv = tid >> 6, lane = tid & 63;          // wv = col-block (gat/gemms)
    const int quad = lane >> 4, lid = lane & 15;
    const int n_mine = n0 + lid;
    const int* gptr = graph + (b * 512 + n_mine) * 512 + quad * 8;
    const float* edp = ed1 + b * 512 + quad * 8;
    const float es_v = es1[b * 512 + n_mine];
    const ushort_t* hb0 = Ht + b * 65536 + (wv * 32 + lid) * 512;
    const ushort_t* hb1 = hb0 + 16 * 512;
    const short8 onesf = {0x3F80, 0x3F80, 0x3F80, 0x3F80, 0x3F80, 0x3F80, 0x3F80, 0x3F80};
    f32x4 acc[2], dsf;
    acc[0] = (f32x4){0.f, 0.f, 0.f, 0.f};
    acc[1] = (f32x4){0.f, 0.f, 0.f, 0.f};
    dsf = (f32x4){0.f, 0.f, 0.f, 0.f};
#pragma unroll 4
    for (int mcc = 0; mcc < 16; mcc++) {
        const int mbase = mcc * 32 + quad * 8;
        int4 ga = *(const int4*)(gptr + mcc * 32);
        int4 gb = *(const int4*)(gptr + mcc * 32 + 4);
        float4 e0v = *(const float4*)(edp + mcc * 32);
        float4 e1v = *(const float4*)(edp + mcc * 32 + 4);
        int gv[8] = {ga.x, ga.y, ga.z, ga.w, gb.x, gb.y, gb.z, gb.w};
        float ev[8] = {e0v.x, e0v.y, e0v.z, e0v.w, e1v.x, e1v.y, e1v.z, e1v.w};
        short8 pk;
#pragma unroll
        for (int j = 0; j < 8; j++) {
            float e = es_v + ev[j];
            e = fmaxf(e, 0.2f * e);
            e = ((gv[j] > 0) | ((mbase + j) == n_mine)) ? e : -1e30f;
            pk[j] = (short)f2bf_t(__expf(e));
        }
        short8 b0 = *(const short8*)&hb0[mbase];
        short8 b1 = *(const short8*)&hb1[mbase];
        acc[0] = __builtin_amdgcn_mfma_f32_16x16x32_bf16(pk, b0, acc[0], 0, 0, 0);
        acc[1] = __builtin_amdgcn_mfma_f32_16x16x32_bf16(pk, b1, acc[1], 0, 0, 0);
        dsf = __builtin_amdgcn_mfma_f32_16x16x32_bf16(pk, onesf, dsf, 0, 0, 0);
    }
#pragma unroll
    for (int reg = 0; reg < 4; reg++) {
        float inv = 1.0f / dsf[reg];
        int rw = quad * 4 + reg;
#pragma unroll
        for (int ch = 0; ch < 2; ch++)
            gbuf[rw * 132 + wv * 32 + ch * 16 + lid] = acc[ch][reg] * inv;
    }
    __syncthreads();
    // ---- LN1 over concat(x,G); ybuf bf16 ----
    const int r = tid >> 4, c16 = tid & 15;
    const float4* xp = (const float4*)(x + (b * 512 + n0 + r) * 128);
    float4 vv4[4];
    float s = 0.f, ss = 0.f;
#pragma unroll
    for (int i = 0; i < 4; i++) {
        int c4 = c16 * 4 + i;
        float4 v = (c4 < 32) ? xp[c4] : *(const float4*)&gbuf[r * 132 + (c4 - 32) * 4];
        vv4[i] = v;
        s += v.x + v.y + v.z + v.w;
        ss += v.x * v.x + v.y * v.y + v.z * v.z + v.w * v.w;
    }
#pragma unroll
    for (int st = 1; st <= 8; st <<= 1) { s += __shfl_xor(s, st); ss += __shfl_xor(ss, st); }
    if (c16 == 0) {
        float mu = s * (1.f / 256.f);
        float var = ss * (1.f / 256.f) - mu * mu;
        mvs[r] = make_float2(mu, rsqrtf(var + 1e-5f));
    }
    __syncthreads();
    {
        float mu = mvs[r].x, rstd = mvs[r].y;
#pragma unroll
        for (int half = 0; half < 2; half++) {
            int g = c16 * 2 + half, c0 = g * 8;
            float va[8] = {vv4[half * 2].x, vv4[half * 2].y, vv4[half * 2].z, vv4[half * 2].w,
                           vv4[half * 2 + 1].x, vv4[half * 2 + 1].y, vv4[half * 2 + 1].z, vv4[half * 2 + 1].w};
            short8 p;
#pragma unroll
            for (int e = 0; e < 8; e++)
                p[e] = (short)f2bf((va[e] - mu) * rstd * g1[c0 + e] + b1[c0 + e]);
            *(short8*)&ybuf[r * 256 + ((g ^ (r & 7)) * 8)] = p;
        }
    }
    __syncthreads();
    // ---- GEMM1: M2 = y @ lin_W + lin_b ----
    short8 af8[8];
#pragma unroll
    for (int ks = 0; ks < 8; ks++)
        af8[ks] = *(const short8*)&ybuf[lid * 256 + (((ks * 4 + quad) ^ (lid & 7)) * 8)];
    f32x4 M2[2];
#pragma unroll
    for (int i = 0; i < 2; i++) {
        int ct = wv + 4 * i;
        const ushort_t* bp = linT + (ct * 16 + lid) * 256 + quad * 8;
        M2[i] = (f32x4){0.f, 0.f, 0.f, 0.f};
#pragma unroll
        for (int ks = 0; ks < 8; ks++) {
            short8 bf = *(const short8*)&bp[ks * 32];
            M2[i] = __builtin_amdgcn_mfma_f32_16x16x32_bf16(af8[ks], bf, M2[i], 0, 0, 0);
        }
        float bias = LB[ct * 16 + lid];
#pragma unroll
        for (int reg = 0; reg < 4; reg++) M2[i][reg] += bias;
        int col = ct * 16 + lid, g = col >> 3, pos = col & 7;
#pragma unroll
        for (int reg = 0; reg < 4; reg++) {
            int rw = quad * 4 + reg;
            abuf[rw * 128 + ((g ^ (rw & 7)) * 8) + pos] = f2bf(M2[i][reg]);
        }
    }
    __syncthreads();
    // ---- T = gelu(m2 @ me_W0 + b0) ----
    short8 at[4];
#pragma unroll
    for (int kc = 0; kc < 4; kc++)
        at[kc] = *(const short8*)&abuf[lid * 128 + (((kc * 4 + quad) ^ (lid & 7)) * 8)];
#pragma unroll
    for (int i = 0; i < 2; i++) {
        int ct = wv + 4 * i;
        const ushort_t* bp = meT0 + (ct * 16 + lid) * 128 + quad * 8;
        f32x4 C = (f32x4){0.f, 0.f, 0.f, 0.f};
#pragma unroll
        for (int kc = 0; kc < 4; kc++) {
            short8 bf = *(const short8*)&bp[kc * 32];
            C = __builtin_amdgcn_mfma_f32_16x16x32_bf16(at[kc], bf, C, 0, 0, 0);
        }
        int col = ct * 16 + lid, g = col >> 3, pos = col & 7;
        float bias = B0[col];
#pragma unroll
        for (int reg = 0; reg < 4; reg++) {
            int rw = quad * 4 + reg;
            tbuf[rw * 128 + ((g ^ (rw & 7)) * 8) + pos] = f2bf(gelu_f(C[reg] + bias));
        }
    }
    __syncthreads();
    // ---- enc = T @ me_W1 + b1 ; R = m2 + enc ; ln2 ----
#pragma unroll
    for (int kc = 0; kc < 4; kc++)
        at[kc] = *(const short8*)&tbuf[lid * 128 + (((kc * 4 + quad) ^ (lid & 7)) * 8)];
    f32x4 R[2];
    float sr[4] = {0.f, 0.f, 0.f, 0.f}, ssr[4] = {0.f, 0.f, 0.f, 0.f};
#pragma unroll
    for (int i = 0; i < 2; i++) {
        int ct = wv + 4 * i;
        const ushort_t* bp = meT1 + (ct * 16 + lid) * 128 + quad * 8;
        f32x4 C = (f32x4){0.f, 0.f, 0.f, 0.f};
#pragma unroll
        for (int kc = 0; kc < 4; kc++) {
            short8 bf = *(const short8*)&bp[kc * 32];
            C = __builtin_amdgcn_mfma_f32_16x16x32_bf16(at[kc], bf, C, 0, 0, 0);
        }
        float bias = B1[ct * 16 + lid];
#pragma unroll
        for (int reg = 0; reg < 4; reg++) {
            float v = M2[i][reg] + C[reg] + bias;
            R[i][reg] = v;
            sr[reg] += v; ssr[reg] += v * v;
        }
    }
#pragma unroll
    for (int st = 1; st <= 8; st <<= 1)
#pragma unroll
        for (int reg = 0; reg < 4; reg++) {
            sr[reg] += __shfl_xor(sr[reg], st);
            ssr[reg] += __shfl_xor(ssr[reg], st);
        }
    if (lid == 0) {
#pragma unroll
        for (int reg = 0; reg < 4; reg++)
            red[wv * 16 + quad * 4 + reg] = make_float2(sr[reg], ssr[reg]);
    }
    __syncthreads();
    float mu2[4], rstd2[4];
#pragma unroll
    for (int reg = 0; reg < 4; reg++) {
        float S = 0.f, SS = 0.f;
#pragma unroll
        for (int w4 = 0; w4 < 4; w4++) {
            float2 p = red[w4 * 16 + quad * 4 + reg];
            S += p.x; SS += p.y;
        }
        mu2[reg] = S * (1.f / 128.f);
        float var = SS * (1.f / 128.f) - mu2[reg] * mu2[reg];
        rstd2[reg] = rsqrtf(var + 1e-5f);
    }
#pragma unroll
    for (int i = 0; i < 2; i++) {
        int col = (wv + 4 * i) * 16 + lid, g = col >> 3, pos = col & 7;
        float gv = g2[col], bv = b2[col];
#pragma unroll
        for (int reg = 0; reg < 4; reg++) {
            int rw = quad * 4 + reg;
            float v = (R[i][reg] - mu2[reg]) * rstd2[reg] * gv + bv;
            tbuf[rw * 128 + ((g ^ (rw & 7)) * 8) + pos] = f2bf(v);
        }
    }
    __syncthreads();
    // ---- V = gelu(r @ oh_W + ob) ; ln3 ; store ----
#pragma unroll
    for (int kc = 0; kc < 4; kc++)
        at[kc] = *(const short8*)&tbuf[lid * 128 + (((kc * 4 + quad) ^ (lid & 7)) * 8)];
    f32x4 V[2];
#pragma unroll
    for (int reg = 0; reg < 4; reg++) { sr[reg] = 0.f; ssr[reg] = 0.f; }
#pragma unroll
    for (int i = 0; i < 2; i++) {
        int ct = wv + 4 * i;
        const ushort_t* bp = ohT + (ct * 16 + lid) * 128 + quad * 8;
        f32x4 C = (f32x4){0.f, 0.f, 0.f, 0.f};
#pragma unroll
        for (int kc = 0; kc < 4; kc++) {
            short8 bf = *(const short8*)&bp[kc * 32];
            C = __builtin_amdgcn_mfma_f32_16x16x32_bf16(at[kc], bf, C, 0, 0, 0);
        }
        float bias = ob[ct * 16 + lid];
#pragma unroll
        for (int reg = 0; reg < 4; reg++) {
            float v = gelu_f(C[reg] + bias);
            V[i][reg] = v;
            sr[reg] += v; ssr[reg] += v * v;
        }
    }
#pragma unroll
    for (int st = 1; st <= 8; st <<= 1)
#pragma unroll
        for (int reg = 0; reg < 4; reg++) {
            sr[reg] += __shfl_xor(sr[reg], st);
            ssr[reg] += __shfl_xor(ssr[reg], st);
        }
    if (lid == 0) {
#pragma unroll
        for (int reg = 0; reg < 4; reg++)
            red[wv * 16 + quad * 4 + reg] = make_float2(sr[reg], ssr[reg]);
    }
    __syncthreads();
#pragma unroll
    for (int reg = 0; reg < 4; reg++) {
        float S = 0.f, SS = 0.f;
#pragma unroll
        for (int w4 = 0; w4 < 4; w4++) {
            float2 p = red[w4 * 16 + quad * 4 + reg];
            S += p.x; SS += p.y;
        }
        mu2[reg] = S * (1.f / 128.f);
        float var = SS * (1.f / 128.f) - mu2[reg] * mu2[reg];
        rstd2[reg] = rsqrtf(var + 1e-5f);
    }
#pragma unroll
    for (int i = 0; i < 2; i++) {
        int col = (wv + 4 * i) * 16 + lid;
        float gv = g3[col], bv = b3[col];
#pragma unroll
        for (int reg = 0; reg < 4; reg++)
            out[(b * 512 + n0 + quad * 4 + reg) * 128 + col] =
                (V[i][reg] - mu2[reg]) * rstd2[reg] * gv + bv;
    }
}

extern "C" void kernel_launch(void* const* d_in, const int* in_sizes, int n_in,
                              void* d_out, int out_size, void* d_ws, size_t ws_size,
                              hipStream_t stream) {
    const float* x      = (const float*)d_in[0];
    const int*   graph  = (const int*)d_in[1];
    const float* a_src0 = (const float*)d_in[3];
    const float* a_dst0 = (const float*)d_in[4];
    const float* a_src1 = (const float*)d_in[6];
    const float* a_dst1 = (const float*)d_in[7];
    float* out = (float*)d_out;

    float* ws  = (float*)d_ws;
    ushort_t* Ht0  = (ushort_t*)ws;               // 2097152 bf16
    ushort_t* Ht1  = Ht0 + 2097152;               // 2097152 bf16
    float*    e0s  = ws + 2097152;                // 65536
    float*    e0d  = e0s + 65536;                 // 65536
    float*    e1s  = e0d + 65536;                 // 16384
    float*    e1d  = e1s + 16384;                 // 16384
    ushort_t* WT   = (ushort_t*)(e1d + 16384);    // 114688 bf16
    ushort_t* linT = WT;                          // 32768
    ushort_t* meT0 = WT + 32768;                  // 16384
    ushort_t* meT1 = WT + 49152;                  // 16384
    ushort_t* ohT  = WT + 65536;                  // 16384
    ushort_t* W0T  = WT + 81920;                  // 16384
    ushort_t* W1T  = WT + 98304;                  // 16384

    prep_wt<<<448, 256, 0, stream>>>((const float*)d_in[10], (const float*)d_in[12],
                                     (const float*)d_in[14], (const float*)d_in[18],
                                     (const float*)d_in[2], (const float*)d_in[5], WT);
    gemm_mfma0<<<1024, 256, 0, stream>>>(x, W0T, Ht0, a_src0, a_dst0, e0s, e0d);
    gat0_gemm<<<dim3(32, 32), 256, 0, stream>>>(Ht0, e0s, e0d, graph, W1T,
                                                a_src1, a_dst1, Ht1, e1s, e1d);
    gat1_head<<<dim3(32, 32), 256, 0, stream>>>(Ht1, e1s, e1d, graph, x,
                                                (const float*)d_in[8], (const float*)d_in[9],
                                                linT, (const float*)d_in[11],
                                                meT0, (const float*)d_in[13],
                                                meT1, (const float*)d_in[15],
                                                (const float*)d_in[16], (const float*)d_in[17],
                                                ohT, (const float*)d_in[19],
                                                (const float*)d_in[20], (const float*)d_in[21],
                                                out);
}

// Round 9
// 223.716 us; speedup vs baseline: 1.0065x; 1.0065x over previous
//
#include <hip/hip_runtime.h>
#include <cmath>

// B=32, N=512, IN=128, HID=32, HEADS=4, OUT=128. fp32 in/out; graph int32.
// 4 dispatches: prep_wt ; gemm_mfma0(x,W0T)->Ht0,e0 ;
//   gat0_gemm(Ht0,e0,graph,W1T)->Ht1,e1 ; gat1_head(Ht1,e1,graph,x,...)->out
// gat m-loops: per-wave double-buffered LDS pipeline, barrier-free.
//   - wave w owns Ht rows w*32..w*32+32; stages 4KB chunks cooperatively
//     (bulk MLP), next chunk's Ht/graph/e prefetched into regs during MFMA.
//   - P computed per-lane in A-frag layout; no shared ps, no __syncthreads.

typedef unsigned short ushort_t;
typedef __attribute__((ext_vector_type(8))) short short8;
typedef __attribute__((ext_vector_type(4))) float f32x4;

__device__ __forceinline__ float gelu_f(float v) {
    return 0.5f * v * (1.0f + erff(v * 0.70710678118654752f));
}
__device__ __forceinline__ ushort_t f2bf(float x) {      // round-to-nearest-even
    union { float f; unsigned u; } v; v.f = x;
    return (ushort_t)((v.u + 0x7FFFu + ((v.u >> 16) & 1u)) >> 16);
}
__device__ __forceinline__ ushort_t f2bf_t(float x) {    // truncate (hot softmax path)
    union { float f; unsigned u; } v; v.f = x;
    return (ushort_t)(v.u >> 16);
}

// ---- prep: bf16-transpose lin_W(256x128) me_W0 me_W1 oh_W W0 W1 (128x128) ---
__global__ __launch_bounds__(256) void prep_wt(const float* __restrict__ lin_W,
        const float* __restrict__ me_W0, const float* __restrict__ me_W1,
        const float* __restrict__ oh_W, const float* __restrict__ W0,
        const float* __restrict__ W1, ushort_t* __restrict__ WT) {
    int i = blockIdx.x * 256 + threadIdx.x;          // 114688 total
    if (i < 32768)       { int c = i >> 8, k = i & 255;                   WT[i] = f2bf(lin_W[k * 128 + c]); }
    else if (i < 49152)  { int j = i - 32768;  int c = j >> 7, k = j & 127; WT[i] = f2bf(me_W0[k * 128 + c]); }
    else if (i < 65536)  { int j = i - 49152;  int c = j >> 7, k = j & 127; WT[i] = f2bf(me_W1[k * 128 + c]); }
    else if (i < 81920)  { int j = i - 65536;  int c = j >> 7, k = j & 127; WT[i] = f2bf(oh_W[k * 128 + c]); }
    else if (i < 98304)  { int j = i - 81920;  int c = j >> 7, k = j & 127; WT[i] = f2bf(W0[k * 128 + c]); }
    else if (i < 114688) { int j = i - 98304;  int c = j >> 7, k = j & 127; WT[i] = f2bf(W1[k * 128 + c]); }
}

// -- 16-row MFMA gemm (R7 version): Ht bf16 = (X@W)^T ; fused e (4 heads) ----
__global__ __launch_bounds__(256) void gemm_mfma0(const float* __restrict__ X,
        const ushort_t* __restrict__ WTr, ushort_t* __restrict__ Ht,
        const float* __restrict__ a_s, const float* __restrict__ a_d,
        float* __restrict__ es, float* __restrict__ ed) {
    __shared__ __align__(16) ushort_t abuf[16 * 128];
    __shared__ __align__(16) ushort_t tb[128 * 24];
    __shared__ float2 ered[8 * 16];
    const int tid = threadIdx.x;
    const int row0 = blockIdx.x * 16;
    const int b = row0 >> 9, m0 = row0 & 511;
    const int w = tid >> 6, lane = tid & 63;
    const int quad = lane >> 4, lid = lane & 15;
    {
        int r = tid >> 4, g = tid & 15;
        const float4* src = (const float4*)(X + (row0 + r) * 128 + g * 8);
        float4 a = src[0], bb = src[1];
        short8 p;
        p[0] = (short)f2bf(a.x);  p[1] = (short)f2bf(a.y);
        p[2] = (short)f2bf(a.z);  p[3] = (short)f2bf(a.w);
        p[4] = (short)f2bf(bb.x); p[5] = (short)f2bf(bb.y);
        p[6] = (short)f2bf(bb.z); p[7] = (short)f2bf(bb.w);
        *(short8*)&abuf[r * 128 + ((g ^ (r & 7)) * 8)] = p;
    }
    __syncthreads();
    short8 af[4];
#pragma unroll
    for (int kc = 0; kc < 4; kc++)
        af[kc] = *(const short8*)&abuf[lid * 128 + (((kc * 4 + quad) ^ (lid & 7)) * 8)];
    f32x4 C[2];
#pragma unroll
    for (int i = 0; i < 2; i++) {
        int ct = w + 4 * i;
        const ushort_t* bp = WTr + (ct * 16 + lid) * 128 + quad * 8;
        C[i] = (f32x4){0.f, 0.f, 0.f, 0.f};
#pragma unroll
        for (int kc = 0; kc < 4; kc++) {
            short8 bf = *(const short8*)&bp[kc * 32];
            C[i] = __builtin_amdgcn_mfma_f32_16x16x32_bf16(af[kc], bf, C[i], 0, 0, 0);
        }
    }
#pragma unroll
    for (int i = 0; i < 2; i++) {
        int ct = w + 4 * i, col = ct * 16 + lid;
        float as_c = a_s[col], ad_c = a_d[col];
        float s0[4], d0[4];
#pragma unroll
        for (int r = 0; r < 4; r++) { s0[r] = C[i][r] * as_c; d0[r] = C[i][r] * ad_c; }
#pragma unroll
        for (int st = 1; st <= 8; st <<= 1)
#pragma unroll
            for (int r = 0; r < 4; r++) {
                s0[r] += __shfl_xor(s0[r], st);
                d0[r] += __shfl_xor(d0[r], st);
            }
        if (lid == 0) {
#pragma unroll
            for (int r = 0; r < 4; r++)
                ered[ct * 16 + quad * 4 + r] = make_float2(s0[r], d0[r]);
        }
#pragma unroll
        for (int r = 0; r < 4; r++)
            tb[col * 24 + quad * 4 + r] = f2bf(C[i][r]);
    }
    __syncthreads();
    if (tid < 64) {
        int row = tid & 15, h = tid >> 4;
        float2 pa = ered[(2 * h) * 16 + row], pb = ered[(2 * h + 1) * 16 + row];
        es[(b * 4 + h) * 512 + m0 + row] = pa.x + pb.x;
        ed[(b * 4 + h) * 512 + m0 + row] = pa.y + pb.y;
    }
    {
        int c = tid >> 1, half = tid & 1;
        *(short8*)&Ht[b * 65536 + c * 512 + m0 + half * 8] = *(const short8*)&tb[c * 24 + half * 8];
    }
}

// ---- K2: gat0 (per-wave pipelined m-loop) -> elu -> gemm vs W1T -> Ht1, e1 --
__global__ __launch_bounds__(256) void gat0_gemm(const ushort_t* __restrict__ Ht0,
        const float* __restrict__ es0, const float* __restrict__ ed0,
        const int* __restrict__ graph, const ushort_t* __restrict__ W1T,
        const float* __restrict__ a_s, const float* __restrict__ a_d,
        ushort_t* __restrict__ Ht1, float* __restrict__ es1, float* __restrict__ ed1) {
    __shared__ __align__(16) char smem[32768];
    ushort_t* hsb  = (ushort_t*)smem;              // gat: 2 bufs x 4 waves x 2048 us
    ushort_t* abuf = (ushort_t*)smem;              // gemm overlay [0,4096)
    ushort_t* tb   = (ushort_t*)(smem + 4096);     // gemm [4096,10240)
    float2*   ered = (float2*)(smem + 10240);      // gemm [10240,11264)
    const int tid = threadIdx.x;
    const int b = blockIdx.y, n0 = blockIdx.x * 16;
    const int wv = tid >> 6, lane = tid & 63;      // wv = head (gat) / col pair (gemm)
    const int quad = lane >> 4, lid = lane & 15;
    const int n_mine = n0 + lid;
    const int sc = lane & 31, sg0 = (lane >> 5) * 4;
    const ushort_t* sp = Ht0 + b * 65536 + (wv * 32 + sc) * 512 + sg0 * 8;
    const int* gp = graph + (b * 512 + n_mine) * 512 + quad * 8;
    const float* edp = ed0 + (b * 4 + wv) * 512 + quad * 8;
    const float es_v = es0[(b * 4 + wv) * 512 + n_mine];
    const short8 onesf = {0x3F80, 0x3F80, 0x3F80, 0x3F80, 0x3F80, 0x3F80, 0x3F80, 0x3F80};
    f32x4 acc[2], dsf;
    acc[0] = (f32x4){0.f, 0.f, 0.f, 0.f};
    acc[1] = (f32x4){0.f, 0.f, 0.f, 0.f};
    dsf = (f32x4){0.f, 0.f, 0.f, 0.f};
    short8 stg[4];
    int4 gr[4];
    float4 er[4];
#pragma unroll
    for (int t = 0; t < 4; t++) stg[t] = *(const short8*)&sp[t * 8];
#pragma unroll
    for (int kc = 0; kc < 2; kc++) {
        gr[kc * 2]     = *(const int4*)(gp + kc * 32);
        gr[kc * 2 + 1] = *(const int4*)(gp + kc * 32 + 4);
        er[kc * 2]     = *(const float4*)(edp + kc * 32);
        er[kc * 2 + 1] = *(const float4*)(edp + kc * 32 + 4);
    }
#pragma unroll 2
    for (int mcc = 0; mcc < 8; mcc++) {
        ushort_t* wb = hsb + (mcc & 1) * 8192 + wv * 2048;
#pragma unroll
        for (int t = 0; t < 4; t++) {
            int g = sg0 + t;
            *(short8*)&wb[sc * 64 + ((g ^ (sc & 7)) * 8)] = stg[t];
        }
        short8 pk[2];
#pragma unroll
        for (int kc = 0; kc < 2; kc++) {
            int mb = mcc * 64 + kc * 32 + quad * 8;
            int gv[8] = {gr[kc * 2].x, gr[kc * 2].y, gr[kc * 2].z, gr[kc * 2].w,
                         gr[kc * 2 + 1].x, gr[kc * 2 + 1].y, gr[kc * 2 + 1].z, gr[kc * 2 + 1].w};
            float ev[8] = {er[kc * 2].x, er[kc * 2].y, er[kc * 2].z, er[kc * 2].w,
                           er[kc * 2 + 1].x, er[kc * 2 + 1].y, er[kc * 2 + 1].z, er[kc * 2 + 1].w};
#pragma unroll
            for (int j = 0; j < 8; j++) {
                float e = es_v + ev[j];
                e = fmaxf(e, 0.2f * e);
                e = ((gv[j] > 0) | ((mb + j) == n_mine)) ? e : -1e30f;
                pk[kc][j] = (short)f2bf_t(__expf(e));
            }
        }
        if (mcc < 7) {
#pragma unroll
            for (int t = 0; t < 4; t++) stg[t] = *(const short8*)&sp[(mcc + 1) * 64 + t * 8];
#pragma unroll
            for (int kc = 0; kc < 2; kc++) {
                gr[kc * 2]     = *(const int4*)(gp + (mcc + 1) * 64 + kc * 32);
                gr[kc * 2 + 1] = *(const int4*)(gp + (mcc + 1) * 64 + kc * 32 + 4);
                er[kc * 2]     = *(const float4*)(edp + (mcc + 1) * 64 + kc * 32);
                er[kc * 2 + 1] = *(const float4*)(edp + (mcc + 1) * 64 + kc * 32 + 4);
            }
        }
#pragma unroll
        for (int kc = 0; kc < 2; kc++) {
            const int gsw = ((kc * 4 + quad) ^ (lid & 7)) * 8;
            short8 b0 = *(const short8*)&wb[lid * 64 + gsw];
            short8 b1 = *(const short8*)&wb[(16 + lid) * 64 + gsw];
            acc[0] = __builtin_amdgcn_mfma_f32_16x16x32_bf16(pk[kc], b0, acc[0], 0, 0, 0);
            acc[1] = __builtin_amdgcn_mfma_f32_16x16x32_bf16(pk[kc], b1, acc[1], 0, 0, 0);
            dsf = __builtin_amdgcn_mfma_f32_16x16x32_bf16(pk[kc], onesf, dsf, 0, 0, 0);
        }
    }
    __syncthreads();                                // all waves done with hsb
    // ---- m = elu(softmax-agg) -> bf16 A-tile ----
#pragma unroll
    for (int reg = 0; reg < 4; reg++) {
        float inv = 1.0f / dsf[reg];
        int rw = quad * 4 + reg;
#pragma unroll
        for (int ch = 0; ch < 2; ch++) {
            float v = acc[ch][reg] * inv;
            v = v > 0.f ? v : expm1f(v);            // ELU
            int col = wv * 32 + ch * 16 + lid;
            abuf[rw * 128 + (((col >> 3) ^ (rw & 7)) * 8) + (col & 7)] = f2bf(v);
        }
    }
    __syncthreads();
    // ---- gemm vs W1T + fused e1 (1 head) + Ht1 ----
    short8 af[4];
#pragma unroll
    for (int kc = 0; kc < 4; kc++)
        af[kc] = *(const short8*)&abuf[lid * 128 + (((kc * 4 + quad) ^ (lid & 7)) * 8)];
    f32x4 C[2];
#pragma unroll
    for (int i = 0; i < 2; i++) {
        int ct = wv + 4 * i;
        const ushort_t* bp = W1T + (ct * 16 + lid) * 128 + quad * 8;
        C[i] = (f32x4){0.f, 0.f, 0.f, 0.f};
#pragma unroll
        for (int kc = 0; kc < 4; kc++) {
            short8 bf = *(const short8*)&bp[kc * 32];
            C[i] = __builtin_amdgcn_mfma_f32_16x16x32_bf16(af[kc], bf, C[i], 0, 0, 0);
        }
    }
#pragma unroll
    for (int i = 0; i < 2; i++) {
        int ct = wv + 4 * i, col = ct * 16 + lid;
        float as_c = a_s[col], ad_c = a_d[col];
        float s0[4], d0[4];
#pragma unroll
        for (int r = 0; r < 4; r++) { s0[r] = C[i][r] * as_c; d0[r] = C[i][r] * ad_c; }
#pragma unroll
        for (int st = 1; st <= 8; st <<= 1)
#pragma unroll
            for (int r = 0; r < 4; r++) {
                s0[r] += __shfl_xor(s0[r], st);
                d0[r] += __shfl_xor(d0[r], st);
            }
        if (lid == 0) {
#pragma unroll
            for (int r = 0; r < 4; r++)
                ered[ct * 16 + quad * 4 + r] = make_float2(s0[r], d0[r]);
        }
#pragma unroll
        for (int r = 0; r < 4; r++)
            tb[col * 24 + quad * 4 + r] = f2bf(C[i][r]);
    }
    __syncthreads();
    if (tid < 16) {
        float S = 0.f, D = 0.f;
#pragma unroll
        for (int ct = 0; ct < 8; ct++) { float2 p = ered[ct * 16 + tid]; S += p.x; D += p.y; }
        es1[b * 512 + n0 + tid] = S;
        ed1[b * 512 + n0 + tid] = D;
    }
    {
        int c = tid >> 1, half = tid & 1;
        *(short8*)&Ht1[b * 65536 + c * 512 + n0 + half * 8] = *(const short8*)&tb[c * 24 + half * 8];
    }
}

// ---- K3: gat1 (per-wave pipelined) -> ln1 -> linear -> MLP -> ln2 -> head ---
__global__ __launch_bounds__(256) void gat1_head(const ushort_t* __restrict__ Ht,
        const float* __restrict__ es1, const float* __restrict__ ed1,
        const int* __restrict__ graph, const float* __restrict__ x,
        const float* __restrict__ g1, const float* __restrict__ b1,
        const ushort_t* __restrict__ linT, const float* __restrict__ LB,
        const ushort_t* __restrict__ meT0, const float* __restrict__ B0,
        const ushort_t* __restrict__ meT1, const float* __restrict__ B1,
        const float* __restrict__ g2, const float* __restrict__ b2,
        const ushort_t* __restrict__ ohT, const float* __restrict__ ob,
        const float* __restrict__ g3, const float* __restrict__ b3,
        float* __restrict__ out) {
    __shared__ __align__(16) char smem[32768];
    ushort_t* hsb  = (ushort_t*)smem;              // gat: 2 bufs x 4 waves x 2048 us
    float*    gbuf = (float*)smem;                 // head [0,8448)
    ushort_t* ybuf = (ushort_t*)(smem + 8448);     // head [8448,16640)
    ushort_t* abuf = (ushort_t*)(smem + 16640);    // head [16640,20736)
    ushort_t* tbuf = (ushort_t*)(smem + 20736);    // head [20736,24832)
    float2*   red  = (float2*)(smem + 24832);      // [24832,25344)
    float2*   mvs  = (float2*)(smem + 25344);      // [25344,25472)
    const int tid = threadIdx.x;
    const int b = blockIdx.y, n0 = blockIdx.x * 16;
    const int wv = tid >> 6, lane = tid & 63;
    const int quad = lane >> 4, lid = lane & 15;
    const int n_mine = n0 + lid;
    const int sc = lane & 31, sg0 = (lane >> 5) * 4;
    const ushort_t* sp = Ht + b * 65536 + (wv * 32 + sc) * 512 + sg0 * 8;
    const int* gp = graph + (b * 512 + n_mine) * 512 + quad * 8;
    const float* edp = ed1 + b * 512 + quad * 8;
    const float es_v = es1[b * 512 + n_mine];
    const short8 onesf = {0x3F80, 0x3F80, 0x3F80, 0x3F80, 0x3F80, 0x3F80, 0x3F80, 0x3F80};
    f32x4 acc[2], dsf;
    acc[0] = (f32x4){0.f, 0.f, 0.f, 0.f};
    acc[1] = (f32x4){0.f, 0.f, 0.f, 0.f};
    dsf = (f32x4){0.f, 0.f, 0.f, 0.f};
    short8 stg[4];
    int4 gr[4];
    float4 er[4];
#pragma unroll
    for (int t = 0; t < 4; t++) stg[t] = *(const short8*)&sp[t * 8];
#pragma unroll
    for (int kc = 0; kc < 2; kc++) {
        gr[kc * 2]     = *(const int4*)(gp + kc * 32);
        gr[kc * 2 + 1] = *(const int4*)(gp + kc * 32 + 4);
        er[kc * 2]     = *(const float4*)(edp + kc * 32);
        er[kc * 2 + 1] = *(const float4*)(edp + kc * 32 + 4);
    }
#pragma unroll 2
    for (int mcc = 0; mcc < 8; mcc++) {
        ushort_t* wb = hsb + (mcc & 1) * 8192 + wv * 2048;
#pragma unroll
        for (int t = 0; t < 4; t++) {
            int g = sg0 + t;
            *(short8*)&wb[sc * 64 + ((g ^ (sc & 7)) * 8)] = stg[t];
        }
        short8 pk[2];
#pragma unroll
        for (int kc = 0; kc < 2; kc++) {
            int mb = mcc * 64 + kc * 32 + quad * 8;
            int gv[8] = {gr[kc * 2].x, gr[kc * 2].y, gr[kc * 2].z, gr[kc * 2].w,
                         gr[kc * 2 + 1].x, gr[kc * 2 + 1].y, gr[kc * 2 + 1].z, gr[kc * 2 + 1].w};
            float ev[8] = {er[kc * 2].x, er[kc * 2].y, er[kc * 2].z, er[kc * 2].w,
                           er[kc * 2 + 1].x, er[kc * 2 + 1].y, er[kc * 2 + 1].z, er[kc * 2 + 1].w};
#pragma unroll
            for (int j = 0; j < 8; j++) {
                float e = es_v + ev[j];
                e = fmaxf(e, 0.2f * e);
                e = ((gv[j] > 0) | ((mb + j) == n_mine)) ? e : -1e30f;
                pk[kc][j] = (short)f2bf_t(__expf(e));
            }
        }
        if (mcc < 7) {
#pragma unroll
            for (int t = 0; t < 4; t++) stg[t] = *(const short8*)&sp[(mcc + 1) * 64 + t * 8];
#pragma unroll
            for (int kc = 0; kc < 2; kc++) {
                gr[kc * 2]     = *(const int4*)(gp + (mcc + 1) * 64 + kc * 32);
                gr[kc * 2 + 1] = *(const int4*)(gp + (mcc + 1) * 64 + kc * 32 + 4);
                er[kc * 2]     = *(const float4*)(edp + (mcc + 1) * 64 + kc * 32);
                er[kc * 2 + 1] = *(const float4*)(edp + (mcc + 1) * 64 + kc * 32 + 4);
            }
        }
#pragma unroll
        for (int kc = 0; kc < 2; kc++) {
            const int gsw = ((kc * 4 + quad) ^ (lid & 7)) * 8;
            short8 b0 = *(const short8*)&wb[lid * 64 + gsw];
            short8 b1 = *(const short8*)&wb[(16 + lid) * 64 + gsw];
            acc[0] = __builtin_amdgcn_mfma_f32_16x16x32_bf16(pk[kc], b0, acc[0], 0, 0, 0);
            acc[1] = __builtin_amdgcn_mfma_f32_16x16x32_bf16(pk[kc], b1, acc[1], 0, 0, 0);
            dsf = __builtin_amdgcn_mfma_f32_16x16x32_bf16(pk[kc], onesf, dsf, 0, 0, 0);
        }
    }
    __syncthreads();                                // all waves done with hsb
#pragma unroll
    for (int reg = 0; reg < 4; reg++) {
        float inv = 1.0f / dsf[reg];
        int rw = quad * 4 + reg;
#pragma unroll
        for (int ch = 0; ch < 2; ch++)
            gbuf[rw * 132 + wv * 32 + ch * 16 + lid] = acc[ch][reg] * inv;
    }
    __syncthreads();
    // ---- LN1 over concat(x,G); ybuf bf16 ----
    const int r = tid >> 4, c16 = tid & 15;
    const float4* xp = (const float4*)(x + (b * 512 + n0 + r) * 128);
    float4 vv4[4];
    float s = 0.f, ss = 0.f;
#pragma unroll
    for (int i = 0; i < 4; i++) {
        int c4 = c16 * 4 + i;
        float4 v = (c4 < 32) ? xp[c4] : *(const float4*)&gbuf[r * 132 + (c4 - 32) * 4];
        vv4[i] = v;
        s += v.x + v.y + v.z + v.w;
        ss += v.x * v.x + v.y * v.y + v.z * v.z + v.w * v.w;
    }
#pragma unroll
    for (int st = 1; st <= 8; st <<= 1) { s += __shfl_xor(s, st); ss += __shfl_xor(ss, st); }
    if (c16 == 0) {
        float mu = s * (1.f / 256.f);
        float var = ss * (1.f / 256.f) - mu * mu;
        mvs[r] = make_float2(mu, rsqrtf(var + 1e-5f));
    }
    __syncthreads();
    {
        float mu = mvs[r].x, rstd = mvs[r].y;
#pragma unroll
        for (int half = 0; half < 2; half++) {
            int g = c16 * 2 + half, c0 = g * 8;
            float va[8] = {vv4[half * 2].x, vv4[half * 2].y, vv4[half * 2].z, vv4[half * 2].w,
                           vv4[half * 2 + 1].x, vv4[half * 2 + 1].y, vv4[half * 2 + 1].z, vv4[half * 2 + 1].w};
            short8 p;
#pragma unroll
            for (int e = 0; e < 8; e++)
                p[e] = (short)f2bf((va[e] - mu) * rstd * g1[c0 + e] + b1[c0 + e]);
            *(short8*)&ybuf[r * 256 + ((g ^ (r & 7)) * 8)] = p;
        }
    }
    __syncthreads();
    // ---- GEMM1: M2 = y @ lin_W + lin_b ----
    short8 af8[8];
#pragma unroll
    for (int ks = 0; ks < 8; ks++)
        af8[ks] = *(const short8*)&ybuf[lid * 256 + (((ks * 4 + quad) ^ (lid & 7)) * 8)];
    f32x4 M2[2];
#pragma unroll
    for (int i = 0; i < 2; i++) {
        int ct = wv + 4 * i;
        const ushort_t* bp = linT + (ct * 16 + lid) * 256 + quad * 8;
        M2[i] = (f32x4){0.f, 0.f, 0.f, 0.f};
#pragma unroll
        for (int ks = 0; ks < 8; ks++) {
            short8 bf = *(const short8*)&bp[ks * 32];
            M2[i] = __builtin_amdgcn_mfma_f32_16x16x32_bf16(af8[ks], bf, M2[i], 0, 0, 0);
        }
        float bias = LB[ct * 16 + lid];
#pragma unroll
        for (int reg = 0; reg < 4; reg++) M2[i][reg] += bias;
        int col = ct * 16 + lid, g = col >> 3, pos = col & 7;
#pragma unroll
        for (int reg = 0; reg < 4; reg++) {
            int rw = quad * 4 + reg;
            abuf[rw * 128 + ((g ^ (rw & 7)) * 8) + pos] = f2bf(M2[i][reg]);
        }
    }
    __syncthreads();
    // ---- T = gelu(m2 @ me_W0 + b0) ----
    short8 at[4];
#pragma unroll
    for (int kc = 0; kc < 4; kc++)
        at[kc] = *(const short8*)&abuf[lid * 128 + (((kc * 4 + quad) ^ (lid & 7)) * 8)];
#pragma unroll
    for (int i = 0; i < 2; i++) {
        int ct = wv + 4 * i;
        const ushort_t* bp = meT0 + (ct * 16 + lid) * 128 + quad * 8;
        f32x4 C = (f32x4){0.f, 0.f, 0.f, 0.f};
#pragma unroll
        for (int kc = 0; kc < 4; kc++) {
            short8 bf = *(const short8*)&bp[kc * 32];
            C = __builtin_amdgcn_mfma_f32_16x16x32_bf16(at[kc], bf, C, 0, 0, 0);
        }
        int col = ct * 16 + lid, g = col >> 3, pos = col & 7;
        float bias = B0[col];
#pragma unroll
        for (int reg = 0; reg < 4; reg++) {
            int rw = quad * 4 + reg;
            tbuf[rw * 128 + ((g ^ (rw & 7)) * 8) + pos] = f2bf(gelu_f(C[reg] + bias));
        }
    }
    __syncthreads();
    // ---- enc = T @ me_W1 + b1 ; R = m2 + enc ; ln2 ----
#pragma unroll
    for (int kc = 0; kc < 4; kc++)
        at[kc] = *(const short8*)&tbuf[lid * 128 + (((kc * 4 + quad) ^ (lid & 7)) * 8)];
    f32x4 R[2];
    float sr[4] = {0.f, 0.f, 0.f, 0.f}, ssr[4] = {0.f, 0.f, 0.f, 0.f};
#pragma unroll
    for (int i = 0; i < 2; i++) {
        int ct = wv + 4 * i;
        const ushort_t* bp = meT1 + (ct * 16 + lid) * 128 + quad * 8;
        f32x4 C = (f32x4){0.f, 0.f, 0.f, 0.f};
#pragma unroll
        for (int kc = 0; kc < 4; kc++) {
            short8 bf = *(const short8*)&bp[kc * 32];
            C = __builtin_amdgcn_mfma_f32_16x16x32_bf16(at[kc], bf, C, 0, 0, 0);
        }
        float bias = B1[ct * 16 + lid];
#pragma unroll
        for (int reg = 0; reg < 4; reg++) {
            float v = M2[i][reg] + C[reg] + bias;
            R[i][reg] = v;
            sr[reg] += v; ssr[reg] += v * v;
        }
    }
#pragma unroll
    for (int st = 1; st <= 8; st <<= 1)
#pragma unroll
        for (int reg = 0; reg < 4; reg++) {
            sr[reg] += __shfl_xor(sr[reg], st);
            ssr[reg] += __shfl_xor(ssr[reg], st);
        }
    if (lid == 0) {
#pragma unroll
        for (int reg = 0; reg < 4; reg++)
            red[wv * 16 + quad * 4 + reg] = make_float2(sr[reg], ssr[reg]);
    }
    __syncthreads();
    float mu2[4], rstd2[4];
#pragma unroll
    for (int reg = 0; reg < 4; reg++) {
        float S = 0.f, SS = 0.f;
#pragma unroll
        for (int w4 = 0; w4 < 4; w4++) {
            float2 p = red[w4 * 16 + quad * 4 + reg];
            S += p.x; SS += p.y;
        }
        mu2[reg] = S * (1.f / 128.f);
        float var = SS * (1.f / 128.f) - mu2[reg] * mu2[reg];
        rstd2[reg] = rsqrtf(var + 1e-5f);
    }
#pragma unroll
    for (int i = 0; i < 2; i++) {
        int col = (wv + 4 * i) * 16 + lid, g = col >> 3, pos = col & 7;
        float gv = g2[col], bv = b2[col];
#pragma unroll
        for (int reg = 0; reg < 4; reg++) {
            int rw = quad * 4 + reg;
            float v = (R[i][reg] - mu2[reg]) * rstd2[reg] * gv + bv;
            tbuf[rw * 128 + ((g ^ (rw & 7)) * 8) + pos] = f2bf(v);
        }
    }
    __syncthreads();
    // ---- V = gelu(r @ oh_W + ob) ; ln3 ; store ----
#pragma unroll
    for (int kc = 0; kc < 4; kc++)
        at[kc] = *(const short8*)&tbuf[lid * 128 + (((kc * 4 + quad) ^ (lid & 7)) * 8)];
    f32x4 V[2];
#pragma unroll
    for (int reg = 0; reg < 4; reg++) { sr[reg] = 0.f; ssr[reg] = 0.f; }
#pragma unroll
    for (int i = 0; i < 2; i++) {
        int ct = wv + 4 * i;
        const ushort_t* bp = ohT + (ct * 16 + lid) * 128 + quad * 8;
        f32x4 C = (f32x4){0.f, 0.f, 0.f, 0.f};
#pragma unroll
        for (int kc = 0; kc < 4; kc++) {
            short8 bf = *(const short8*)&bp[kc * 32];
            C = __builtin_amdgcn_mfma_f32_16x16x32_bf16(at[kc], bf, C, 0, 0, 0);
        }
        float bias = ob[ct * 16 + lid];
#pragma unroll
        for (int reg = 0; reg < 4; reg++) {
            float v = gelu_f(C[reg] + bias);
            V[i][reg] = v;
            sr[reg] += v; ssr[reg] += v * v;
        }
    }
#pragma unroll
    for (int st = 1; st <= 8; st <<= 1)
#pragma unroll
        for (int reg = 0; reg < 4; reg++) {
            sr[reg] += __shfl_xor(sr[reg], st);
            ssr[reg] += __shfl_xor(ssr[reg], st);
        }
    if (lid == 0) {
#pragma unroll
        for (int reg = 0; reg < 4; reg++)
            red[wv * 16 + quad * 4 + reg] = make_float2(sr[reg], ssr[reg]);
    }
    __syncthreads();
#pragma unroll
    for (int reg = 0; reg < 4; reg++) {
        float S = 0.f, SS = 0.f;
#pragma unroll
        for (int w4 = 0; w4 < 4; w4++) {
            float2 p = red[w4 * 16 + quad * 4 + reg];
            S += p.x; SS += p.y;
        }
        mu2[reg] = S * (1.f / 128.f);
        float var = SS * (1.f / 128.f) - mu2[reg] * mu2[reg];
        rstd2[reg] = rsqrtf(var + 1e-5f);
    }
#pragma unroll
    for (int i = 0; i < 2; i++) {
        int col = (wv + 4 * i) * 16 + lid;
        float gv = g3[col], bv = b3[col];
#pragma unroll
        for (int reg = 0; reg < 4; reg++)
            out[(b * 512 + n0 + quad * 4 + reg) * 128 + col] =
                (V[i][reg] - mu2[reg]) * rstd2[reg] * gv + bv;
    }
}

extern "C" void kernel_launch(void* const* d_in, const int* in_sizes, int n_in,
                              void* d_out, int out_size, void* d_ws, size_t ws_size,
                              hipStream_t stream) {
    const float* x      = (const float*)d_in[0];
    const int*   graph  = (const int*)d_in[1];
    const float* a_src0 = (const float*)d_in[3];
    const float* a_dst0 = (const float*)d_in[4];
    const float* a_src1 = (const float*)d_in[6];
    const float* a_dst1 = (const float*)d_in[7];
    float* out = (float*)d_out;

    float* ws  = (float*)d_ws;
    ushort_t* Ht0  = (ushort_t*)ws;               // 2097152 bf16
    ushort_t* Ht1  = Ht0 + 2097152;               // 2097152 bf16
    float*    e0s  = ws + 2097152;                // 65536
    float*    e0d  = e0s + 65536;                 // 65536
    float*    e1s  = e0d + 65536;                 // 16384
    float*    e1d  = e1s + 16384;                 // 16384
    ushort_t* WT   = (ushort_t*)(e1d + 16384);    // 114688 bf16
    ushort_t* linT = WT;                          // 32768
    ushort_t* meT0 = WT + 32768;                  // 16384
    ushort_t* meT1 = WT + 49152;                  // 16384
    ushort_t* ohT  = WT + 65536;                  // 16384
    ushort_t* W0T  = WT + 81920;                  // 16384
    ushort_t* W1T  = WT + 98304;                  // 16384

    prep_wt<<<448, 256, 0, stream>>>((const float*)d_in[10], (const float*)d_in[12],
                                     (const float*)d_in[14], (const float*)d_in[18],
                                     (const float*)d_in[2], (const float*)d_in[5], WT);
    gemm_mfma0<<<1024, 256, 0, stream>>>(x, W0T, Ht0, a_src0, a_dst0, e0s, e0d);
    gat0_gemm<<<dim3(32, 32), 256, 0, stream>>>(Ht0, e0s, e0d, graph, W1T,
                                                a_src1, a_dst1, Ht1, e1s, e1d);
    gat1_head<<<dim3(32, 32), 256, 0, stream>>>(Ht1, e1s, e1d, graph, x,
                                                (const float*)d_in[8], (const float*)d_in[9],
                                                linT, (const float*)d_in[11],
                                                meT0, (const float*)d_in[13],
                                                meT1, (const float*)d_in[15],
                                                (const float*)d_in[16], (const float*)d_in[17],
                                                ohT, (const float*)d_in[19],
                                                (const float*)d_in[20], (const float*)d_in[21],
                                                out);
}

// Round 10
// 196.618 us; speedup vs baseline: 1.1452x; 1.1378x over previous
//
#include <hip/hip_runtime.h>
#include <cmath>

// B=32, N=512, IN=128, HID=32, HEADS=4, OUT=128. fp32 in/out; graph int32.
// 5 dispatches: prep_wt ; pack_graph (32MB int32 -> 1MB bitmask, streaming) ;
//   gemm_mfma0(x,W0T)->Ht0,e0 ; gat0_gemm(Ht0,e0,gmask,W1T)->Ht1,e1 ;
//   gat1_head(Ht1,e1,gmask,x,...)->out
// gat P-comp tests bits from the L3-resident mask instead of scattered cold
// int32 graph reads (the R7..R9 latency culprit).

typedef unsigned short ushort_t;
typedef __attribute__((ext_vector_type(8))) short short8;
typedef __attribute__((ext_vector_type(4))) float f32x4;

__device__ __forceinline__ float gelu_f(float v) {
    return 0.5f * v * (1.0f + erff(v * 0.70710678118654752f));
}
__device__ __forceinline__ ushort_t f2bf(float x) {      // round-to-nearest-even
    union { float f; unsigned u; } v; v.f = x;
    return (ushort_t)((v.u + 0x7FFFu + ((v.u >> 16) & 1u)) >> 16);
}
__device__ __forceinline__ ushort_t f2bf_t(float x) {    // truncate (hot softmax path)
    union { float f; unsigned u; } v; v.f = x;
    return (ushort_t)(v.u >> 16);
}

// ---- prep: bf16-transpose lin_W(256x128) me_W0 me_W1 oh_W W0 W1 (128x128) ---
__global__ __launch_bounds__(256) void prep_wt(const float* __restrict__ lin_W,
        const float* __restrict__ me_W0, const float* __restrict__ me_W1,
        const float* __restrict__ oh_W, const float* __restrict__ W0,
        const float* __restrict__ W1, ushort_t* __restrict__ WT) {
    int i = blockIdx.x * 256 + threadIdx.x;          // 114688 total
    if (i < 32768)       { int c = i >> 8, k = i & 255;                   WT[i] = f2bf(lin_W[k * 128 + c]); }
    else if (i < 49152)  { int j = i - 32768;  int c = j >> 7, k = j & 127; WT[i] = f2bf(me_W0[k * 128 + c]); }
    else if (i < 65536)  { int j = i - 49152;  int c = j >> 7, k = j & 127; WT[i] = f2bf(me_W1[k * 128 + c]); }
    else if (i < 81920)  { int j = i - 65536;  int c = j >> 7, k = j & 127; WT[i] = f2bf(oh_W[k * 128 + c]); }
    else if (i < 98304)  { int j = i - 81920;  int c = j >> 7, k = j & 127; WT[i] = f2bf(W0[k * 128 + c]); }
    else if (i < 114688) { int j = i - 98304;  int c = j >> 7, k = j & 127; WT[i] = f2bf(W1[k * 128 + c]); }
}

// ---- pack graph>0 into bitmask: gmask[(b*512+n)*16 + w] bit j = m=w*32+j ----
__global__ __launch_bounds__(256) void pack_graph(const int* __restrict__ g,
                                                  unsigned* __restrict__ gm) {
    int idx = blockIdx.x * 256 + threadIdx.x;        // 262144 = 32*512*16
    const int4* gp = (const int4*)g + (size_t)idx * 8;
    unsigned m = 0;
#pragma unroll
    for (int q = 0; q < 8; q++) {
        int4 v = gp[q];
        m |= (unsigned)(v.x > 0) << (q * 4 + 0);
        m |= (unsigned)(v.y > 0) << (q * 4 + 1);
        m |= (unsigned)(v.z > 0) << (q * 4 + 2);
        m |= (unsigned)(v.w > 0) << (q * 4 + 3);
    }
    gm[idx] = m;
}

// -- 16-row MFMA gemm: Ht bf16 = (X@W)^T ; fused e_src/e_dst (4 heads) -------
__global__ __launch_bounds__(256) void gemm_mfma0(const float* __restrict__ X,
        const ushort_t* __restrict__ WTr, ushort_t* __restrict__ Ht,
        const float* __restrict__ a_s, const float* __restrict__ a_d,
        float* __restrict__ es, float* __restrict__ ed) {
    __shared__ __align__(16) ushort_t abuf[16 * 128];
    __shared__ __align__(16) ushort_t tb[128 * 24];
    __shared__ float2 ered[8 * 16];
    const int tid = threadIdx.x;
    const int row0 = blockIdx.x * 16;
    const int b = row0 >> 9, m0 = row0 & 511;
    const int w = tid >> 6, lane = tid & 63;
    const int quad = lane >> 4, lid = lane & 15;
    {
        int r = tid >> 4, g = tid & 15;
        const float4* src = (const float4*)(X + (row0 + r) * 128 + g * 8);
        float4 a = src[0], bb = src[1];
        short8 p;
        p[0] = (short)f2bf(a.x);  p[1] = (short)f2bf(a.y);
        p[2] = (short)f2bf(a.z);  p[3] = (short)f2bf(a.w);
        p[4] = (short)f2bf(bb.x); p[5] = (short)f2bf(bb.y);
        p[6] = (short)f2bf(bb.z); p[7] = (short)f2bf(bb.w);
        *(short8*)&abuf[r * 128 + ((g ^ (r & 7)) * 8)] = p;
    }
    __syncthreads();
    short8 af[4];
#pragma unroll
    for (int kc = 0; kc < 4; kc++)
        af[kc] = *(const short8*)&abuf[lid * 128 + (((kc * 4 + quad) ^ (lid & 7)) * 8)];
    f32x4 C[2];
#pragma unroll
    for (int i = 0; i < 2; i++) {
        int ct = w + 4 * i;
        const ushort_t* bp = WTr + (ct * 16 + lid) * 128 + quad * 8;
        C[i] = (f32x4){0.f, 0.f, 0.f, 0.f};
#pragma unroll
        for (int kc = 0; kc < 4; kc++) {
            short8 bf = *(const short8*)&bp[kc * 32];
            C[i] = __builtin_amdgcn_mfma_f32_16x16x32_bf16(af[kc], bf, C[i], 0, 0, 0);
        }
    }
#pragma unroll
    for (int i = 0; i < 2; i++) {
        int ct = w + 4 * i, col = ct * 16 + lid;
        float as_c = a_s[col], ad_c = a_d[col];
        float s0[4], d0[4];
#pragma unroll
        for (int r = 0; r < 4; r++) { s0[r] = C[i][r] * as_c; d0[r] = C[i][r] * ad_c; }
#pragma unroll
        for (int st = 1; st <= 8; st <<= 1)
#pragma unroll
            for (int r = 0; r < 4; r++) {
                s0[r] += __shfl_xor(s0[r], st);
                d0[r] += __shfl_xor(d0[r], st);
            }
        if (lid == 0) {
#pragma unroll
            for (int r = 0; r < 4; r++)
                ered[ct * 16 + quad * 4 + r] = make_float2(s0[r], d0[r]);
        }
#pragma unroll
        for (int r = 0; r < 4; r++)
            tb[col * 24 + quad * 4 + r] = f2bf(C[i][r]);
    }
    __syncthreads();
    if (tid < 64) {
        int row = tid & 15, h = tid >> 4;
        float2 pa = ered[(2 * h) * 16 + row], pb = ered[(2 * h + 1) * 16 + row];
        es[(b * 4 + h) * 512 + m0 + row] = pa.x + pb.x;
        ed[(b * 4 + h) * 512 + m0 + row] = pa.y + pb.y;
    }
    {
        int c = tid >> 1, half = tid & 1;
        *(short8*)&Ht[b * 65536 + c * 512 + m0 + half * 8] = *(const short8*)&tb[c * 24 + half * 8];
    }
}

// ---- K2: gat0 (bitmask P) -> elu -> gemm vs W1T -> Ht1, e1 ------------------
__global__ __launch_bounds__(256) void gat0_gemm(const ushort_t* __restrict__ Ht0,
        const float* __restrict__ es0, const float* __restrict__ ed0,
        const unsigned* __restrict__ gmask, const ushort_t* __restrict__ W1T,
        const float* __restrict__ a_s, const float* __restrict__ a_d,
        ushort_t* __restrict__ Ht1, float* __restrict__ es1, float* __restrict__ ed1) {
    __shared__ __align__(16) char smem[33024];
    ushort_t* hsb  = (ushort_t*)smem;              // [0,16384)  gat phase
    ushort_t* ps   = (ushort_t*)(smem + 16384);    // [16384,24576) gat
    float*    eds  = (float*)(smem + 24576);       // [24576,32768) gat
    float*    ess  = (float*)(smem + 32768);       // 256B gat
    ushort_t* abuf = (ushort_t*)(smem + 16384);    // gemm phase (over ps)
    ushort_t* tb   = (ushort_t*)(smem + 24576);    // gemm (over eds)
    float2*   ered = (float2*)(smem + 30720);      // gemm
    const int tid = threadIdx.x;
    const int b = blockIdx.y, n0 = blockIdx.x * 16;
    const int wv = tid >> 6, lane = tid & 63;      // wv = head (gat) / col pair (gemm)
    const int quad = lane >> 4, lid = lane & 15;
    const int pn = tid >> 4, pg = (tid >> 1) & 7, ph = tid & 1;
    for (int i = tid; i < 2048; i += 256) eds[i] = ed0[b * 2048 + i];
    if (tid < 64) ess[tid] = es0[b * 2048 + (tid >> 4) * 512 + n0 + (tid & 15)];
    const unsigned* gmrow = gmask + (b * 512 + n0 + pn) * 16;
    const short8 onesf = {0x3F80, 0x3F80, 0x3F80, 0x3F80, 0x3F80, 0x3F80, 0x3F80, 0x3F80};
    f32x4 acc[2], dsf;
    acc[0] = (f32x4){0.f, 0.f, 0.f, 0.f};
    acc[1] = (f32x4){0.f, 0.f, 0.f, 0.f};
    dsf = (f32x4){0.f, 0.f, 0.f, 0.f};
    for (int mc = 0; mc < 512; mc += 64) {
        __syncthreads();
        {
            const ushort_t* src = Ht0 + b * 65536 + mc;
            for (int u = tid; u < 1024; u += 256) {
                int c = u >> 3, g = u & 7;
                *(short8*)&hsb[c * 64 + ((g ^ (c & 7)) * 8)] = *(const short8*)&src[c * 512 + g * 8];
            }
        }
        {
            int ng = n0 + pn, mbase = mc + pg * 8;
            unsigned mw = gmrow[mbase >> 5];
            unsigned mbits = (mw >> (mbase & 31)) & 0xffu;
            if ((unsigned)(ng - mbase) < 8u) mbits |= 1u << (ng - mbase);   // self-loop
#pragma unroll
            for (int hi = 0; hi < 2; hi++) {
                int hh = ph * 2 + hi;
                float es_v = ess[hh * 16 + pn];
                float4 e0v = *(const float4*)&eds[hh * 512 + mbase];
                float4 e1v = *(const float4*)&eds[hh * 512 + mbase + 4];
                float ev[8] = {e0v.x, e0v.y, e0v.z, e0v.w, e1v.x, e1v.y, e1v.z, e1v.w};
                short8 pk;
#pragma unroll
                for (int j = 0; j < 8; j++) {
                    float e = es_v + ev[j];
                    e = fmaxf(e, 0.2f * e);
                    e = ((mbits >> j) & 1u) ? e : -1e30f;
                    pk[j] = (short)f2bf_t(__expf(e));
                }
                int prow = hh * 16 + pn;
                *(short8*)&ps[prow * 64 + ((pg ^ (prow & 7)) * 8)] = pk;
            }
        }
        __syncthreads();
#pragma unroll
        for (int kc = 0; kc < 2; kc++) {
            const int gsw = ((kc * 4 + quad) ^ (lid & 7)) * 8;
            short8 a = *(const short8*)&ps[(wv * 16 + lid) * 64 + gsw];
            short8 b0 = *(const short8*)&hsb[(wv * 32 + lid) * 64 + gsw];
            short8 b1 = *(const short8*)&hsb[(wv * 32 + 16 + lid) * 64 + gsw];
            acc[0] = __builtin_amdgcn_mfma_f32_16x16x32_bf16(a, b0, acc[0], 0, 0, 0);
            acc[1] = __builtin_amdgcn_mfma_f32_16x16x32_bf16(a, b1, acc[1], 0, 0, 0);
            dsf = __builtin_amdgcn_mfma_f32_16x16x32_bf16(a, onesf, dsf, 0, 0, 0);
        }
    }
    __syncthreads();                                // gat LDS reads done; abuf overlay safe
    // ---- m = elu(softmax-agg) -> bf16 A-tile ----
#pragma unroll
    for (int reg = 0; reg < 4; reg++) {
        float inv = 1.0f / dsf[reg];
        int rw = quad * 4 + reg;
#pragma unroll
        for (int ch = 0; ch < 2; ch++) {
            float v = acc[ch][reg] * inv;
            v = v > 0.f ? v : expm1f(v);            // ELU
            int col = wv * 32 + ch * 16 + lid;
            abuf[rw * 128 + (((col >> 3) ^ (rw & 7)) * 8) + (col & 7)] = f2bf(v);
        }
    }
    __syncthreads();
    // ---- gemm vs W1T + fused e1 (1 head) + Ht1 ----
    short8 af[4];
#pragma unroll
    for (int kc = 0; kc < 4; kc++)
        af[kc] = *(const short8*)&abuf[lid * 128 + (((kc * 4 + quad) ^ (lid & 7)) * 8)];
    f32x4 C[2];
#pragma unroll
    for (int i = 0; i < 2; i++) {
        int ct = wv + 4 * i;
        const ushort_t* bp = W1T + (ct * 16 + lid) * 128 + quad * 8;
        C[i] = (f32x4){0.f, 0.f, 0.f, 0.f};
#pragma unroll
        for (int kc = 0; kc < 4; kc++) {
            short8 bf = *(const short8*)&bp[kc * 32];
            C[i] = __builtin_amdgcn_mfma_f32_16x16x32_bf16(af[kc], bf, C[i], 0, 0, 0);
        }
    }
#pragma unroll
    for (int i = 0; i < 2; i++) {
        int ct = wv + 4 * i, col = ct * 16 + lid;
        float as_c = a_s[col], ad_c = a_d[col];
        float s0[4], d0[4];
#pragma unroll
        for (int r = 0; r < 4; r++) { s0[r] = C[i][r] * as_c; d0[r] = C[i][r] * ad_c; }
#pragma unroll
        for (int st = 1; st <= 8; st <<= 1)
#pragma unroll
            for (int r = 0; r < 4; r++) {
                s0[r] += __shfl_xor(s0[r], st);
                d0[r] += __shfl_xor(d0[r], st);
            }
        if (lid == 0) {
#pragma unroll
            for (int r = 0; r < 4; r++)
                ered[ct * 16 + quad * 4 + r] = make_float2(s0[r], d0[r]);
        }
#pragma unroll
        for (int r = 0; r < 4; r++)
            tb[col * 24 + quad * 4 + r] = f2bf(C[i][r]);
    }
    __syncthreads();
    if (tid < 16) {
        float S = 0.f, D = 0.f;
#pragma unroll
        for (int ct = 0; ct < 8; ct++) { float2 p = ered[ct * 16 + tid]; S += p.x; D += p.y; }
        es1[b * 512 + n0 + tid] = S;
        ed1[b * 512 + n0 + tid] = D;
    }
    {
        int c = tid >> 1, half = tid & 1;
        *(short8*)&Ht1[b * 65536 + c * 512 + n0 + half * 8] = *(const short8*)&tb[c * 24 + half * 8];
    }
}

// ---- K3: gat1 (bitmask P) -> ln1 -> linear -> MLP -> ln2 -> head -> ln3 -----
__global__ __launch_bounds__(256) void gat1_head(const ushort_t* __restrict__ Ht,
        const float* __restrict__ es1, const float* __restrict__ ed1,
        const unsigned* __restrict__ gmask, const float* __restrict__ x,
        const float* __restrict__ g1, const float* __restrict__ b1,
        const ushort_t* __restrict__ linT, const float* __restrict__ LB,
        const ushort_t* __restrict__ meT0, const float* __restrict__ B0,
        const ushort_t* __restrict__ meT1, const float* __restrict__ B1,
        const float* __restrict__ g2, const float* __restrict__ b2,
        const ushort_t* __restrict__ ohT, const float* __restrict__ ob,
        const float* __restrict__ g3, const float* __restrict__ b3,
        float* __restrict__ out) {
    __shared__ __align__(16) char smem[25472];
    ushort_t* hsb  = (ushort_t*)smem;              // [0,16384) gat phase
    ushort_t* ps   = (ushort_t*)(smem + 16384);    // 2KB gat
    float*    eds  = (float*)(smem + 18432);       // 2KB gat
    float*    ess  = (float*)(smem + 20480);       // 64B gat
    ushort_t* ybuf = (ushort_t*)smem;              // [0,8192) head (over hsb)
    ushort_t* abuf = (ushort_t*)(smem + 8192);     // 4KB head
    ushort_t* tbuf = (ushort_t*)(smem + 12288);    // 4KB head
    float*    gbuf = (float*)(smem + 16384);       // 8448B head (over ps/eds/ess)
    float2*   red  = (float2*)(smem + 24832);      // 512B
    float2*   mvs  = (float2*)(smem + 25344);      // 128B
    const int tid = threadIdx.x;
    const int b = blockIdx.y, n0 = blockIdx.x * 16;
    const int wv = tid >> 6, lane = tid & 63;
    const int quad = lane >> 4, lid = lane & 15;
    for (int i = tid; i < 512; i += 256) eds[i] = ed1[b * 512 + i];
    if (tid < 16) ess[tid] = es1[b * 512 + n0 + tid];
    const unsigned* gmrow = gmask + (b * 512 + n0 + (tid >> 3)) * 16;
    const short8 onesf = {0x3F80, 0x3F80, 0x3F80, 0x3F80, 0x3F80, 0x3F80, 0x3F80, 0x3F80};
    f32x4 acc[2], dsf;
    acc[0] = (f32x4){0.f, 0.f, 0.f, 0.f};
    acc[1] = (f32x4){0.f, 0.f, 0.f, 0.f};
    dsf = (f32x4){0.f, 0.f, 0.f, 0.f};
    for (int mc = 0; mc < 512; mc += 64) {
        __syncthreads();
        {
            const ushort_t* src = Ht + b * 65536 + mc;
            for (int u = tid; u < 1024; u += 256) {
                int c = u >> 3, g = u & 7;
                *(short8*)&hsb[c * 64 + ((g ^ (c & 7)) * 8)] = *(const short8*)&src[c * 512 + g * 8];
            }
        }
        if (tid < 128) {
            int pn = tid >> 3, pg = tid & 7;
            int ng = n0 + pn, mbase = mc + pg * 8;
            unsigned mw = gmrow[mbase >> 5];
            unsigned mbits = (mw >> (mbase & 31)) & 0xffu;
            if ((unsigned)(ng - mbase) < 8u) mbits |= 1u << (ng - mbase);   // self-loop
            float4 e0v = *(const float4*)&eds[mbase & 511];
            float4 e1v = *(const float4*)&eds[(mbase & 511) + 4];
            float ev[8] = {e0v.x, e0v.y, e0v.z, e0v.w, e1v.x, e1v.y, e1v.z, e1v.w};
            float es_v = ess[pn];
            short8 pk;
#pragma unroll
            for (int j = 0; j < 8; j++) {
                float e = es_v + ev[j];
                e = fmaxf(e, 0.2f * e);
                e = ((mbits >> j) & 1u) ? e : -1e30f;
                pk[j] = (short)f2bf_t(__expf(e));
            }
            *(short8*)&ps[pn * 64 + ((pg ^ (pn & 7)) * 8)] = pk;
        }
        __syncthreads();
#pragma unroll
        for (int kc = 0; kc < 2; kc++) {
            const int gsw = ((kc * 4 + quad) ^ (lid & 7)) * 8;
            short8 a = *(const short8*)&ps[lid * 64 + gsw];
            short8 b0 = *(const short8*)&hsb[(wv * 32 + lid) * 64 + gsw];
            short8 b1 = *(const short8*)&hsb[(wv * 32 + 16 + lid) * 64 + gsw];
            acc[0] = __builtin_amdgcn_mfma_f32_16x16x32_bf16(a, b0, acc[0], 0, 0, 0);
            acc[1] = __builtin_amdgcn_mfma_f32_16x16x32_bf16(a, b1, acc[1], 0, 0, 0);
            dsf = __builtin_amdgcn_mfma_f32_16x16x32_bf16(a, onesf, dsf, 0, 0, 0);
        }
    }
    __syncthreads();                                // gat LDS dead
#pragma unroll
    for (int reg = 0; reg < 4; reg++) {
        float inv = 1.0f / dsf[reg];
        int rw = quad * 4 + reg;
#pragma unroll
        for (int ch = 0; ch < 2; ch++)
            gbuf[rw * 132 + wv * 32 + ch * 16 + lid] = acc[ch][reg] * inv;
    }
    __syncthreads();
    // ---- LN1 over concat(x,G); ybuf bf16 ----
    const int r = tid >> 4, c16 = tid & 15;
    const float4* xp = (const float4*)(x + (b * 512 + n0 + r) * 128);
    float4 vv4[4];
    float s = 0.f, ss = 0.f;
#pragma unroll
    for (int i = 0; i < 4; i++) {
        int c4 = c16 * 4 + i;
        float4 v = (c4 < 32) ? xp[c4] : *(const float4*)&gbuf[r * 132 + (c4 - 32) * 4];
        vv4[i] = v;
        s += v.x + v.y + v.z + v.w;
        ss += v.x * v.x + v.y * v.y + v.z * v.z + v.w * v.w;
    }
#pragma unroll
    for (int st = 1; st <= 8; st <<= 1) { s += __shfl_xor(s, st); ss += __shfl_xor(ss, st); }
    if (c16 == 0) {
        float mu = s * (1.f / 256.f);
        float var = ss * (1.f / 256.f) - mu * mu;
        mvs[r] = make_float2(mu, rsqrtf(var + 1e-5f));
    }
    __syncthreads();
    {
        float mu = mvs[r].x, rstd = mvs[r].y;
#pragma unroll
        for (int half = 0; half < 2; half++) {
            int g = c16 * 2 + half, c0 = g * 8;
            float va[8] = {vv4[half * 2].x, vv4[half * 2].y, vv4[half * 2].z, vv4[half * 2].w,
                           vv4[half * 2 + 1].x, vv4[half * 2 + 1].y, vv4[half * 2 + 1].z, vv4[half * 2 + 1].w};
            short8 p;
#pragma unroll
            for (int e = 0; e < 8; e++)
                p[e] = (short)f2bf((va[e] - mu) * rstd * g1[c0 + e] + b1[c0 + e]);
            *(short8*)&ybuf[r * 256 + ((g ^ (r & 7)) * 8)] = p;
        }
    }
    __syncthreads();
    // ---- GEMM1: M2 = y @ lin_W + lin_b ----
    short8 af8[8];
#pragma unroll
    for (int ks = 0; ks < 8; ks++)
        af8[ks] = *(const short8*)&ybuf[lid * 256 + (((ks * 4 + quad) ^ (lid & 7)) * 8)];
    f32x4 M2[2];
#pragma unroll
    for (int i = 0; i < 2; i++) {
        int ct = wv + 4 * i;
        const ushort_t* bp = linT + (ct * 16 + lid) * 256 + quad * 8;
        M2[i] = (f32x4){0.f, 0.f, 0.f, 0.f};
#pragma unroll
        for (int ks = 0; ks < 8; ks++) {
            short8 bf = *(const short8*)&bp[ks * 32];
            M2[i] = __builtin_amdgcn_mfma_f32_16x16x32_bf16(af8[ks], bf, M2[i], 0, 0, 0);
        }
        float bias = LB[ct * 16 + lid];
#pragma unroll
        for (int reg = 0; reg < 4; reg++) M2[i][reg] += bias;
        int col = ct * 16 + lid, g = col >> 3, pos = col & 7;
#pragma unroll
        for (int reg = 0; reg < 4; reg++) {
            int rw = quad * 4 + reg;
            abuf[rw * 128 + ((g ^ (rw & 7)) * 8) + pos] = f2bf(M2[i][reg]);
        }
    }
    __syncthreads();
    // ---- T = gelu(m2 @ me_W0 + b0) ----
    short8 at[4];
#pragma unroll
    for (int kc = 0; kc < 4; kc++)
        at[kc] = *(const short8*)&abuf[lid * 128 + (((kc * 4 + quad) ^ (lid & 7)) * 8)];
#pragma unroll
    for (int i = 0; i < 2; i++) {
        int ct = wv + 4 * i;
        const ushort_t* bp = meT0 + (ct * 16 + lid) * 128 + quad * 8;
        f32x4 C = (f32x4){0.f, 0.f, 0.f, 0.f};
#pragma unroll
        for (int kc = 0; kc < 4; kc++) {
            short8 bf = *(const short8*)&bp[kc * 32];
            C = __builtin_amdgcn_mfma_f32_16x16x32_bf16(at[kc], bf, C, 0, 0, 0);
        }
        int col = ct * 16 + lid, g = col >> 3, pos = col & 7;
        float bias = B0[col];
#pragma unroll
        for (int reg = 0; reg < 4; reg++) {
            int rw = quad * 4 + reg;
            tbuf[rw * 128 + ((g ^ (rw & 7)) * 8) + pos] = f2bf(gelu_f(C[reg] + bias));
        }
    }
    __syncthreads();
    // ---- enc = T @ me_W1 + b1 ; R = m2 + enc ; ln2 ----
#pragma unroll
    for (int kc = 0; kc < 4; kc++)
        at[kc] = *(const short8*)&tbuf[lid * 128 + (((kc * 4 + quad) ^ (lid & 7)) * 8)];
    f32x4 R[2];
    float sr[4] = {0.f, 0.f, 0.f, 0.f}, ssr[4] = {0.f, 0.f, 0.f, 0.f};
#pragma unroll
    for (int i = 0; i < 2; i++) {
        int ct = wv + 4 * i;
        const ushort_t* bp = meT1 + (ct * 16 + lid) * 128 + quad * 8;
        f32x4 C = (f32x4){0.f, 0.f, 0.f, 0.f};
#pragma unroll
        for (int kc = 0; kc < 4; kc++) {
            short8 bf = *(const short8*)&bp[kc * 32];
            C = __builtin_amdgcn_mfma_f32_16x16x32_bf16(at[kc], bf, C, 0, 0, 0);
        }
        float bias = B1[ct * 16 + lid];
#pragma unroll
        for (int reg = 0; reg < 4; reg++) {
            float v = M2[i][reg] + C[reg] + bias;
            R[i][reg] = v;
            sr[reg] += v; ssr[reg] += v * v;
        }
    }
#pragma unroll
    for (int st = 1; st <= 8; st <<= 1)
#pragma unroll
        for (int reg = 0; reg < 4; reg++) {
            sr[reg] += __shfl_xor(sr[reg], st);
            ssr[reg] += __shfl_xor(ssr[reg], st);
        }
    if (lid == 0) {
#pragma unroll
        for (int reg = 0; reg < 4; reg++)
            red[wv * 16 + quad * 4 + reg] = make_float2(sr[reg], ssr[reg]);
    }
    __syncthreads();
    float mu2[4], rstd2[4];
#pragma unroll
    for (int reg = 0; reg < 4; reg++) {
        float S = 0.f, SS = 0.f;
#pragma unroll
        for (int w4 = 0; w4 < 4; w4++) {
            float2 p = red[w4 * 16 + quad * 4 + reg];
            S += p.x; SS += p.y;
        }
        mu2[reg] = S * (1.f / 128.f);
        float var = SS * (1.f / 128.f) - mu2[reg] * mu2[reg];
        rstd2[reg] = rsqrtf(var + 1e-5f);
    }
#pragma unroll
    for (int i = 0; i < 2; i++) {
        int col = (wv + 4 * i) * 16 + lid, g = col >> 3, pos = col & 7;
        float gv = g2[col], bv = b2[col];
#pragma unroll
        for (int reg = 0; reg < 4; reg++) {
            int rw = quad * 4 + reg;
            float v = (R[i][reg] - mu2[reg]) * rstd2[reg] * gv + bv;
            tbuf[rw * 128 + ((g ^ (rw & 7)) * 8) + pos] = f2bf(v);
        }
    }
    __syncthreads();
    // ---- V = gelu(r @ oh_W + ob) ; ln3 ; store ----
#pragma unroll
    for (int kc = 0; kc < 4; kc++)
        at[kc] = *(const short8*)&tbuf[lid * 128 + (((kc * 4 + quad) ^ (lid & 7)) * 8)];
    f32x4 V[2];
#pragma unroll
    for (int reg = 0; reg < 4; reg++) { sr[reg] = 0.f; ssr[reg] = 0.f; }
#pragma unroll
    for (int i = 0; i < 2; i++) {
        int ct = wv + 4 * i;
        const ushort_t* bp = ohT + (ct * 16 + lid) * 128 + quad * 8;
        f32x4 C = (f32x4){0.f, 0.f, 0.f, 0.f};
#pragma unroll
        for (int kc = 0; kc < 4; kc++) {
            short8 bf = *(const short8*)&bp[kc * 32];
            C = __builtin_amdgcn_mfma_f32_16x16x32_bf16(at[kc], bf, C, 0, 0, 0);
        }
        float bias = ob[ct * 16 + lid];
#pragma unroll
        for (int reg = 0; reg < 4; reg++) {
            float v = gelu_f(C[reg] + bias);
            V[i][reg] = v;
            sr[reg] += v; ssr[reg] += v * v;
        }
    }
#pragma unroll
    for (int st = 1; st <= 8; st <<= 1)
#pragma unroll
        for (int reg = 0; reg < 4; reg++) {
            sr[reg] += __shfl_xor(sr[reg], st);
            ssr[reg] += __shfl_xor(ssr[reg], st);
        }
    if (lid == 0) {
#pragma unroll
        for (int reg = 0; reg < 4; reg++)
            red[wv * 16 + quad * 4 + reg] = make_float2(sr[reg], ssr[reg]);
    }
    __syncthreads();
#pragma unroll
    for (int reg = 0; reg < 4; reg++) {
        float S = 0.f, SS = 0.f;
#pragma unroll
        for (int w4 = 0; w4 < 4; w4++) {
            float2 p = red[w4 * 16 + quad * 4 + reg];
            S += p.x; SS += p.y;
        }
        mu2[reg] = S * (1.f / 128.f);
        float var = SS * (1.f / 128.f) - mu2[reg] * mu2[reg];
        rstd2[reg] = rsqrtf(var + 1e-5f);
    }
#pragma unroll
    for (int i = 0; i < 2; i++) {
        int col = (wv + 4 * i) * 16 + lid;
        float gv = g3[col], bv = b3[col];
#pragma unroll
        for (int reg = 0; reg < 4; reg++)
            out[(b * 512 + n0 + quad * 4 + reg) * 128 + col] =
                (V[i][reg] - mu2[reg]) * rstd2[reg] * gv + bv;
    }
}

extern "C" void kernel_launch(void* const* d_in, const int* in_sizes, int n_in,
                              void* d_out, int out_size, void* d_ws, size_t ws_size,
                              hipStream_t stream) {
    const float* x      = (const float*)d_in[0];
    const int*   graph  = (const int*)d_in[1];
    const float* a_src0 = (const float*)d_in[3];
    const float* a_dst0 = (const float*)d_in[4];
    const float* a_src1 = (const float*)d_in[6];
    const float* a_dst1 = (const float*)d_in[7];
    float* out = (float*)d_out;

    float* ws  = (float*)d_ws;
    ushort_t* Ht0  = (ushort_t*)ws;               // 2097152 bf16
    ushort_t* Ht1  = Ht0 + 2097152;               // 2097152 bf16
    float*    e0s  = ws + 2097152;                // 65536
    float*    e0d  = e0s + 65536;                 // 65536
    float*    e1s  = e0d + 65536;                 // 16384
    float*    e1d  = e1s + 16384;                 // 16384
    ushort_t* WT   = (ushort_t*)(e1d + 16384);    // 114688 bf16
    ushort_t* linT = WT;                          // 32768
    ushort_t* meT0 = WT + 32768;                  // 16384
    ushort_t* meT1 = WT + 49152;                  // 16384
    ushort_t* ohT  = WT + 65536;                  // 16384
    ushort_t* W0T  = WT + 81920;                  // 16384
    ushort_t* W1T  = WT + 98304;                  // 16384
    unsigned* gmask = (unsigned*)(WT + 114688);   // 262144 uint32 = 1 MB

    prep_wt<<<448, 256, 0, stream>>>((const float*)d_in[10], (const float*)d_in[12],
                                     (const float*)d_in[14], (const float*)d_in[18],
                                     (const float*)d_in[2], (const float*)d_in[5], WT);
    pack_graph<<<1024, 256, 0, stream>>>(graph, gmask);
    gemm_mfma0<<<1024, 256, 0, stream>>>(x, W0T, Ht0, a_src0, a_dst0, e0s, e0d);
    gat0_gemm<<<dim3(32, 32), 256, 0, stream>>>(Ht0, e0s, e0d, gmask, W1T,
                                                a_src1, a_dst1, Ht1, e1s, e1d);
    gat1_head<<<dim3(32, 32), 256, 0, stream>>>(Ht1, e1s, e1d, gmask, x,
                                                (const float*)d_in[8], (const float*)d_in[9],
                                                linT, (const float*)d_in[11],
                                                meT0, (const float*)d_in[13],
                                                meT1, (const float*)d_in[15],
                                                (const float*)d_in[16], (const float*)d_in[17],
                                                ohT, (const float*)d_in[19],
                                                (const float*)d_in[20], (const float*)d_in[21],
                                                out);
}